// Round 6
// baseline (177.516 us; speedup 1.0000x reference)
//
#include <hip/hip_runtime.h>
#include <hip/hip_bf16.h>
#include <cmath>

// Problem constants
#define N_TOK 16384   // 4*4096
#define DM    1024
#define CH    256
#define SGRID 16
#define NTP   24      // padded n-tiles in ws (21 real: 16 W1 + 5 score)
// wsB layout (ushort): [((kk*24 + nt)*64 + lane)*8 + j] = bf16(B[k][n])
//   k = kk*32 + (lane>>4)*8 + j, n = nt*16 + (lane&15), kk in [0,32)

typedef __attribute__((ext_vector_type(8))) short short8;
typedef __attribute__((ext_vector_type(4))) float floatx4;

__device__ __forceinline__ unsigned short f2bf(float f) {
  union { float f; unsigned int u; } v; v.f = f;
  unsigned int r = v.u + 0x7FFFu + ((v.u >> 16) & 1u);  // RNE
  return (unsigned short)(r >> 16);
}

__device__ __forceinline__ short8 cvt8(float4 u, float4 v) {
  union { short8 s; __hip_bfloat162 h[4]; } r;
  r.h[0] = __float22bfloat162_rn(make_float2(u.x, u.y));
  r.h[1] = __float22bfloat162_rn(make_float2(u.z, u.w));
  r.h[2] = __float22bfloat162_rn(make_float2(v.x, v.y));
  r.h[3] = __float22bfloat162_rn(make_float2(v.z, v.w));
  return r.s;
}

__device__ __forceinline__ float bf2f(unsigned short b) {
  union { unsigned int u; float f; } v; v.u = ((unsigned int)b) << 16; return v.f;
}

__device__ __forceinline__ float calibrate(float s, const float* __restrict__ kn, float temp_eff) {
  float nrm = 1.0f / (1.0f + expf(-s / temp_eff));
  float idxf = nrm * 7.0f;
  int il = (int)idxf; if (il > 6) il = 6;
  float tt = idxf - (float)il;
  float lo = kn[il], hi = kn[il + 1];
  return lo + tt * (hi - lo);
}

// ---------------- K0: prep swizzled B (grid 32 = one block per kk) ----------------
__global__ __launch_bounds__(256) void prep_kernel(
    const float* __restrict__ sig_raw, const float* __restrict__ w1,
    unsigned short* __restrict__ wsB) {
  __shared__ float Wt[32][260];
  __shared__ float St[64][33];
  int kk = blockIdx.x, tid = threadIdx.x;
  {
    int r = tid >> 3, c0 = (tid & 7) * 32;
    const float* src = w1 + (size_t)(kk * 32 + r) * CH + c0;
#pragma unroll
    for (int i = 0; i < 8; ++i)
      *(float4*)(&Wt[r][c0 + 4 * i]) = *(const float4*)(src + 4 * i);
  }
  {
    int t = tid >> 2, c0 = (tid & 3) * 8;
    const float* src = sig_raw + (size_t)t * DM + kk * 32 + c0;
#pragma unroll
    for (int i = 0; i < 8; ++i) {
      float rr = src[i];
      St[t][c0 + i] = (rr > 0.3f) ? 1.f : ((rr < -0.3f) ? -1.f : 0.f);
    }
  }
  __syncthreads();
#pragma unroll
  for (int i = 0; i < 4; ++i) {
    int idx = i * 256 + tid;
    int nt = idx >> 6, lane = idx & 63;
    int q = lane >> 4, l = lane & 15;
    short8 v;
#pragma unroll
    for (int j = 0; j < 8; ++j) v[j] = (short)f2bf(Wt[q * 8 + j][nt * 16 + l]);
    *(short8*)(wsB + ((size_t)(kk * NTP + nt) * 64 + lane) * 8) = v;
  }
#pragma unroll
  for (int i = 0; i < 2; ++i) {
    int idx = i * 256 + tid;
    if (idx < 320) {
      int nt = 16 + (idx >> 6), lane = idx & 63;
      int q = lane >> 4, l = lane & 15;
      int n = nt * 16 + l;
      short8 v;
#pragma unroll
      for (int j = 0; j < 8; ++j) {
        int kl = q * 8 + j;
        float val = 0.f;
        if (n < 264) {
          float s = 0.f;
#pragma unroll
          for (int m = 0; m < 8; ++m) s += St[(n - 256) * 8 + m][kl];
          val = (s > 0.f) ? 1.f : ((s < 0.f) ? -1.f : 0.f);
        } else if (n < 328) {
          val = St[n - 264][kl];
        }
        v[j] = (short)f2bf(val);
      }
      *(short8*)(wsB + ((size_t)(kk * NTP + nt) * 64 + lane) * 8) = v;
    }
  }
}

// ---------------- K1: fused, wave-group phase-offset pipeline ----------------
// R6: grid 256 (64 tok/block), 1024 threads = 2 groups x 8 waves, 1 block/CU.
// Group g owns tokens [g*32, g*32+32) with PRIVATE LDS regions. Phases offset
// by one stage so G1's HBM reads overlap G0's K (LDS), and G0's HBM writes
// overlap G1's K. Overlap is cross-WAVE (separate vmcnt FIFOs) -- the
// mechanism R3/R5's in-wave pipelining could not use. Compute bodies are the
// R2-verified 8-wave versions (bit-identical per-token math, absmax 0.03125).
//   A: stage0         | idle
//   B: K0             | stage1
//   C: route0 (1 wv)  | K1
//   D: LN0 (writes)   | route1 (1 wv)
//   E: idle           | LN1 (writes)

#define LOADK(XB, kk, b0, b1, b2r, av)                                      \
  {                                                                         \
    const char* bp = bBase + (size_t)(kk) * (NTP * 1024);                   \
    b0 = *(const short8*)(bp);                                              \
    b1 = *(const short8*)(bp + 8192);                                       \
    if (wg < 5) b2r = *(const short8*)(bp + 16384);                         \
    unsigned cpos = ((unsigned)((kk) * 4 + quad) ^ sw) << 3;                \
    _Pragma("unroll") for (int mt = 0; mt < 2; ++mt)                        \
        av[mt] = *(const short8*)((XB) + mt * 16384 + arow + cpos);         \
  }

#define COMPUTE(b0, b1, b2r, av)                                            \
  {                                                                         \
    _Pragma("unroll") for (int mt = 0; mt < 2; ++mt) {                      \
      acc0[mt] = __builtin_amdgcn_mfma_f32_16x16x32_bf16(av[mt], b0, acc0[mt], 0, 0, 0); \
      acc1[mt] = __builtin_amdgcn_mfma_f32_16x16x32_bf16(av[mt], b1, acc1[mt], 0, 0, 0); \
    }                                                                       \
    if (wg < 5) {                                                           \
      _Pragma("unroll") for (int mt = 0; mt < 2; ++mt)                      \
        acc2[mt] = __builtin_amdgcn_mfma_f32_16x16x32_bf16(av[mt], b2r, acc2[mt], 0, 0, 0); \
    }                                                                       \
  }

// Stage 32 tokens of group G into Xsh[G] (bf16, XOR-swizzled). 512 threads.
#define STAGE(G)                                                            \
  {                                                                         \
    const float* baseg = x + (size_t)(m0 + (G) * 32) * DM;                  \
    _Pragma("unroll") for (int i2 = 0; i2 < 8; ++i2) {                      \
      int cg = gt + 512 * i2;                                               \
      float4 p = *(const float4*)(baseg + cg * 8);                          \
      float4 q = *(const float4*)(baseg + cg * 8 + 4);                      \
      int row = cg >> 7, cir = cg & 127;                                    \
      int pos = cir ^ (row & 7);                                            \
      *(short8*)(&Xsh[G][row * 1024 + pos * 8]) = cvt8(p, q);               \
    }                                                                       \
  }

// K-loop + scores + comp partials for group G (R2-verified 8-wave body).
#define KLOOP(G)                                                            \
  {                                                                         \
    floatx4 acc0[2], acc1[2], acc2[2];                                      \
    _Pragma("unroll") for (int mt = 0; mt < 2; ++mt) {                      \
      acc0[mt] = (floatx4){0.f, 0.f, 0.f, 0.f};                             \
      acc1[mt] = (floatx4){0.f, 0.f, 0.f, 0.f};                             \
      acc2[mt] = (floatx4){0.f, 0.f, 0.f, 0.f};                             \
    }                                                                       \
    const unsigned short* XB = &Xsh[G][0];                                  \
    short8 bA0, bA1, bA2, bB0, bB1, bB2, aA[2], aB_[2];                     \
    LOADK(XB, 0, bA0, bA1, bA2, aA);                                        \
    _Pragma("unroll 1") for (int kk = 0; kk < 30; kk += 2) {                \
      LOADK(XB, kk + 1, bB0, bB1, bB2, aB_);                                \
      COMPUTE(bA0, bA1, bA2, aA);                                           \
      LOADK(XB, kk + 2, bA0, bA1, bA2, aA);                                 \
      COMPUTE(bB0, bB1, bB2, aB_);                                          \
    }                                                                       \
    LOADK(XB, 31, bB0, bB1, bB2, aB_);                                      \
    COMPUTE(bA0, bA1, bA2, aA);                                             \
    COMPUTE(bB0, bB1, bB2, aB_);                                            \
    if (wg < 5) {                                                           \
      int sc = wg * 16 + l15;                                               \
      if (sc < 72) {                                                        \
        _Pragma("unroll") for (int mt = 0; mt < 2; ++mt)                    \
          _Pragma("unroll") for (int r = 0; r < 4; ++r)                     \
            Ssc[G][mt * 16 + quad * 4 + r][sc] = acc2[mt][r];               \
      }                                                                     \
    }                                                                       \
    {                                                                       \
      int colA = wg * 16 + l15;                                             \
      int colB = 128 + wg * 16 + l15;                                       \
      float b1cA = b1v[colA], w20A = w2[2 * colA], w21A = w2[2 * colA + 1]; \
      float b1cB = b1v[colB], w20B = w2[2 * colB], w21B = w2[2 * colB + 1]; \
      float q0[2][4], q1[2][4];                                             \
      _Pragma("unroll") for (int mt = 0; mt < 2; ++mt)                      \
        _Pragma("unroll") for (int r = 0; r < 4; ++r) {                     \
          float hA = acc0[mt][r] + b1cA;                                    \
          hA = 0.5f * hA * (1.0f + erff(hA * 0.7071067811865475f));         \
          float hB = acc1[mt][r] + b1cB;                                    \
          hB = 0.5f * hB * (1.0f + erff(hB * 0.7071067811865475f));         \
          q0[mt][r] = hA * w20A + hB * w20B;                                \
          q1[mt][r] = hA * w21A + hB * w21B;                                \
        }                                                                   \
      _Pragma("unroll") for (int m = 1; m < 16; m <<= 1)                    \
        _Pragma("unroll") for (int mt = 0; mt < 2; ++mt)                    \
          _Pragma("unroll") for (int r = 0; r < 4; ++r) {                   \
            q0[mt][r] += __shfl_xor(q0[mt][r], m);                          \
            q1[mt][r] += __shfl_xor(q1[mt][r], m);                          \
          }                                                                 \
      if (l15 == 0) {                                                       \
        _Pragma("unroll") for (int mt = 0; mt < 2; ++mt)                    \
          _Pragma("unroll") for (int r = 0; r < 4; ++r) {                   \
            Psh[G][wg][mt * 16 + quad * 4 + r][0] = q0[mt][r];              \
            Psh[G][wg][mt * 16 + quad * 4 + r][1] = q1[mt][r];              \
          }                                                                 \
      }                                                                     \
    }                                                                       \
  }

// Routing + spline for group G: one wave (wg==0), lanes 0..31 = local rows.
#define ROUTE(G)                                                            \
  if (wg == 0 && lane < 32) {                                               \
    int row = lane;                                                         \
    float s0 = b2[0], s1 = b2[1];                                           \
    _Pragma("unroll") for (int j = 0; j < 8; ++j) {                         \
      s0 += Psh[G][j][row][0];                                              \
      s1 += Psh[G][j][row][1];                                              \
    }                                                                       \
    float c0 = tanhf(s0), c1 = tanhf(s1);                                   \
    float temp_eff = temperature[0] + 1e-6f;                                \
    int cid = 0; float best = -1e30f;                                       \
    _Pragma("unroll") for (int c = 0; c < 8; ++c) {                         \
      float g2v = calibrate(Ssc[G][row][c], knots, temp_eff);               \
      if (g2v > best) { best = g2v; cid = c; }                              \
    }                                                                       \
    int lidx = 0; best = -1e30f;                                            \
    _Pragma("unroll") for (int j = 0; j < 8; ++j) {                         \
      float g2v = calibrate(Ssc[G][row][8 + cid * 8 + j], knots, temp_eff); \
      if (g2v > best) { best = g2v; lidx = j; }                             \
    }                                                                       \
    int t = cid * 8 + lidx;                                                 \
    float mag = sb2[t];                                                     \
    _Pragma("unroll") for (int g2 = 0; g2 < SGRID; ++g2) {                  \
      float hv = c0 * sw1[t * 32 + g2] + c1 * sw1[t * 32 + 16 + g2] + sb1[t * 16 + g2]; \
      hv = fmaxf(hv, 0.f);                                                  \
      mag += hv * sw2[t * 16 + g2];                                         \
    }                                                                       \
    ScaleS[G][row] = mag * oscale[0];                                       \
    TidxS[G][row] = t;                                                      \
  }

// Residual + LN for group G: 8 waves x 4 local rows; writes out.
#define LNOUT(G)                                                            \
  _Pragma("unroll 1") for (int rr = 0; rr < 4; ++rr) {                      \
    int row = wg * 4 + rr;                                                  \
    int r7 = row & 7;                                                       \
    float scale = ScaleS[G][row];                                           \
    const float* dr = dirs + (size_t)TidxS[G][row] * DM + lane * 16;        \
    const unsigned short* xrow = &Xsh[G][row * 1024];                       \
    short8 h0 = *(const short8*)(xrow + (unsigned)((2 * lane) ^ r7) * 8);   \
    short8 h1 = *(const short8*)(xrow + (unsigned)((2 * lane + 1) ^ r7) * 8); \
    float fv[16];                                                           \
    float ssum = 0.f, ssq = 0.f;                                            \
    _Pragma("unroll") for (int i = 0; i < 4; ++i) {                         \
      float4 d4 = *(const float4*)(dr + 4 * i);                             \
      float xa = bf2f((unsigned short)((i < 2 ? h0[i * 4 + 0] : h1[(i - 2) * 4 + 0]))); \
      float xb = bf2f((unsigned short)((i < 2 ? h0[i * 4 + 1] : h1[(i - 2) * 4 + 1]))); \
      float xc = bf2f((unsigned short)((i < 2 ? h0[i * 4 + 2] : h1[(i - 2) * 4 + 2]))); \
      float xd = bf2f((unsigned short)((i < 2 ? h0[i * 4 + 3] : h1[(i - 2) * 4 + 3]))); \
      fv[4 * i + 0] = xa + scale * d4.x;                                    \
      fv[4 * i + 1] = xb + scale * d4.y;                                    \
      fv[4 * i + 2] = xc + scale * d4.z;                                    \
      fv[4 * i + 3] = xd + scale * d4.w;                                    \
      ssum += fv[4 * i + 0] + fv[4 * i + 1] + fv[4 * i + 2] + fv[4 * i + 3]; \
      ssq += fv[4 * i + 0] * fv[4 * i + 0] + fv[4 * i + 1] * fv[4 * i + 1]  \
           + fv[4 * i + 2] * fv[4 * i + 2] + fv[4 * i + 3] * fv[4 * i + 3]; \
    }                                                                       \
    _Pragma("unroll") for (int m = 1; m < 64; m <<= 1) {                    \
      ssum += __shfl_xor(ssum, m);                                          \
      ssq += __shfl_xor(ssq, m);                                            \
    }                                                                       \
    float mu = ssum * (1.0f / 1024.0f);                                     \
    float var = ssq * (1.0f / 1024.0f) - mu * mu;                           \
    float inv = rsqrtf(var + 1e-5f);                                        \
    float* orow = out + (size_t)(m0 + (G) * 32 + row) * DM + lane * 16;     \
    const float* gp = gma + lane * 16;                                      \
    const float* bp2 = bta + lane * 16;                                     \
    _Pragma("unroll") for (int i = 0; i < 4; ++i) {                         \
      float4 g4 = *(const float4*)(gp + 4 * i);                             \
      float4 b4 = *(const float4*)(bp2 + 4 * i);                            \
      float4 o;                                                             \
      o.x = (fv[4 * i + 0] - mu) * inv * g4.x + b4.x;                       \
      o.y = (fv[4 * i + 1] - mu) * inv * g4.y + b4.y;                       \
      o.z = (fv[4 * i + 2] - mu) * inv * g4.z + b4.z;                       \
      o.w = (fv[4 * i + 3] - mu) * inv * g4.w + b4.w;                       \
      *(float4*)(orow + 4 * i) = o;                                         \
    }                                                                       \
  }

__global__ __launch_bounds__(1024, 4) void fused_kernel(
    const float* __restrict__ x, const unsigned short* __restrict__ wsB,
    const float* __restrict__ b1v, const float* __restrict__ w2,
    const float* __restrict__ b2, const float* __restrict__ knots,
    const float* __restrict__ temperature, const float* __restrict__ sw1,
    const float* __restrict__ sb1, const float* __restrict__ sw2,
    const float* __restrict__ sb2, const float* __restrict__ dirs,
    const float* __restrict__ gma, const float* __restrict__ bta,
    const float* __restrict__ oscale, float* __restrict__ out) {
  __shared__ unsigned short Xsh[2][32 * 1024];  // 2 x 64 KB, swizzled bf16
  __shared__ float Ssc[2][32][73];              // 2 x 9.3 KB scores
  __shared__ float Psh[2][8][32][2];            // 2 x 2 KB comp partials
  __shared__ float ScaleS[2][32];
  __shared__ int   TidxS[2][32];

  int tid = threadIdx.x;
  int wave = tid >> 6, lane = tid & 63, quad = lane >> 4, l15 = lane & 15;
  int g = wave >> 3, wg = wave & 7;             // group, wave-in-group
  int gt = tid & 511;                           // thread-in-group
  int m0 = blockIdx.x * 64;

  const char* bBase = (const char*)wsB + wg * 1024 + lane * 16;
  int arow = l15 * 1024;
  unsigned sw = (unsigned)(l15 & 7);

  // ---- phase A: G0 stages; G1 idle ----
  if (g == 0) { STAGE(0); }
  __syncthreads();

  // ---- phase B: G0 K-loop (LDS/L2)  ||  G1 stage (HBM read) ----
  if (g == 0) { KLOOP(0); } else { STAGE(1); }
  __syncthreads();

  // ---- phase C: G0 route (1 wave)  ||  G1 K-loop ----
  if (g == 0) { ROUTE(0); } else { KLOOP(1); }
  __syncthreads();

  // ---- phase D: G0 LN (HBM write)  ||  G1 route (1 wave) ----
  if (g == 0) { LNOUT(0); } else { ROUTE(1); }
  __syncthreads();

  // ---- phase E: G1 LN (HBM write) ----
  if (g == 1) { LNOUT(1); }
}

extern "C" void kernel_launch(void* const* d_in, const int* in_sizes, int n_in,
                              void* d_out, int out_size, void* d_ws, size_t ws_size,
                              hipStream_t stream) {
  const float* x      = (const float*)d_in[0];
  const float* sigraw = (const float*)d_in[1];
  const float* knots  = (const float*)d_in[2];
  const float* temp   = (const float*)d_in[3];
  const float* cw1    = (const float*)d_in[4];
  const float* cb1    = (const float*)d_in[5];
  const float* cw2    = (const float*)d_in[6];
  const float* cb2    = (const float*)d_in[7];
  const float* sw1    = (const float*)d_in[8];
  const float* sb1    = (const float*)d_in[9];
  const float* sw2    = (const float*)d_in[10];
  const float* sb2    = (const float*)d_in[11];
  const float* dirs   = (const float*)d_in[12];
  const float* gma    = (const float*)d_in[13];
  const float* bta    = (const float*)d_in[14];
  const float* oscale = (const float*)d_in[15];
  float* out = (float*)d_out;

  unsigned short* wsB = (unsigned short*)d_ws;   // 1,572,864 B

  hipLaunchKernelGGL(prep_kernel, dim3(32), dim3(256), 0, stream,
                     sigraw, cw1, wsB);
  hipLaunchKernelGGL(fused_kernel, dim3(N_TOK / 64), dim3(1024), 0, stream,
                     x, wsB, cb1, cw2, cb2, knots, temp,
                     sw1, sb1, sw2, sb2, dirs, gma, bta, oscale, out);
}